// Round 3
// baseline (4320.436 us; speedup 1.0000x reference)
//
#include <hip/hip_runtime.h>
#include <cstdint>
#include <cstddef>

#define B_   32
#define T_   128
#define H_   1024
#define V_   32000
#define NBLK 256
#define NTHR 256
#define JB   4        // hidden columns per block -> 12 W_hh rows

// LDS layout (floats):
//   Wl  [12][1024]  12288   (W_hh tile, resident across all 128 steps)
//   red [256][100]  25600   (k-split partial spill; 400B row stride -> bank walk)
//   ghl [12][32]      384   (reduced gh tile)
#define LDS_WL_OFF   0
#define LDS_RED_OFF  (12*1024)
#define LDS_GHL_OFF  (12*1024 + 256*100)
#define LDS_FLOATS   (12*1024 + 256*100 + 12*32)

__global__ __launch_bounds__(NTHR) void gru_persist(
    const float* __restrict__ Whh,   // (3072,1024)
    const float* __restrict__ bhh,   // (3072)
    const float* __restrict__ Wih,   // (3072,32000)
    const float* __restrict__ bih,   // (3072)
    const int*   __restrict__ xs,    // (B,T)
    float*       __restrict__ hA,    // (B,H) ping
    float*       __restrict__ hB,    // (B,H) pong
    int*         __restrict__ flags, // (NBLK*32) zeroed before launch
    float*       __restrict__ outp,  // (B,T,H)
    float*       __restrict__ hidout)// (B,H)
{
    extern __shared__ float lds[];
    float* Wl  = lds + LDS_WL_OFF;
    float* red = lds + LDS_RED_OFF;
    float* ghl = lds + LDS_GHL_OFF;

    const int tid = threadIdx.x;
    const int bid = (int)blockIdx.x;
    const int j0  = bid * JB;

    // ---- stage W_hh tile into LDS ONCE (12 rows x 1024, float4 coalesced) ----
    #pragma unroll
    for (int i = 0; i < 12; ++i) {
        const int idx = i * NTHR + tid;   // float4 index 0..3071
        const int r   = idx >> 8;         // row 0..11
        const int kv  = idx & 255;
        const int g   = r >> 2, jj = r & 3;
        ((float4*)(Wl + r * H_))[kv] =
            ((const float4*)(Whh + (size_t)(g*H_ + j0 + jj) * H_))[kv];
    }

    const int gjj = tid & 3;   // gate-phase column-within-block
    const int gb  = tid >> 2;  // gate-phase batch
    const int kq  = tid & 63;  // GEMM k-slice lane
    const int bq  = tid >> 6;  // GEMM batch quad (wave id)

    // reduce-thread constants
    float rbias = 0.f;
    if (tid < 96) {
        const int r = tid >> 3;
        rbias = bhh[(r >> 2) * H_ + j0 + (r & 3)];
    }

    // gate-phase constants + gather prefetch for t=0
    const size_t gr0 = (size_t)(0*H_ + j0 + gjj) * V_;
    const size_t gr1 = (size_t)(1*H_ + j0 + gjj) * V_;
    const size_t gr2 = (size_t)(2*H_ + j0 + gjj) * V_;
    float bih0 = 0.f, bih1 = 0.f, bih2 = 0.f;
    float nxg0 = 0.f, nxg1 = 0.f, nxg2 = 0.f;
    if (tid < 128) {
        bih0 = bih[0*H_ + j0 + gjj];
        bih1 = bih[1*H_ + j0 + gjj];
        bih2 = bih[2*H_ + j0 + gjj];
        const int tok = xs[gb * T_];
        nxg0 = Wih[gr0 + tok];
        nxg1 = Wih[gr1 + tok];
        nxg2 = Wih[gr2 + tok];
    }

    __syncthreads();   // W tile ready

    for (int t = 0; t < T_; ++t) {
        const float* __restrict__ hcur = (t & 1) ? hB : hA;
        float*       __restrict__ hnxt = (t & 1) ? hA : hB;

        // consume prefetched gather; issue h_old load early
        const float xg0 = nxg0 + bih0;
        const float xg1 = nxg1 + bih1;
        const float xg2 = nxg2 + bih2;
        float hold = 0.f;
        if (tid < 128 && t > 0) hold = hcur[(size_t)gb * H_ + j0 + gjj];

        // issue NEXT step's scattered W_ih gather; latency hides under GEMM
        if (tid < 128 && t + 1 < T_) {
            const int tok = xs[gb * T_ + t + 1];
            nxg0 = Wih[gr0 + tok];
            nxg1 = Wih[gr1 + tok];
            nxg2 = Wih[gr2 + tok];
        }

        // ---- GEMM: gh(12 x 32) = W(12x1024) . h(32x1024)^T, 64-way k-split ----
        float acc[12][8];
        #pragma unroll
        for (int r = 0; r < 12; ++r)
            #pragma unroll
            for (int bb = 0; bb < 8; ++bb) acc[r][bb] = 0.f;

        if (t > 0) {
            #pragma unroll
            for (int c = 0; c < 4; ++c) {
                const int k = kq * 4 + c * 256;
                float4 h4[8];
                #pragma unroll
                for (int bb = 0; bb < 8; ++bb)
                    h4[bb] = *(const float4*)(hcur + (size_t)(bq*8 + bb) * H_ + k);
                float4 w4[12];
                #pragma unroll
                for (int r = 0; r < 12; ++r)
                    w4[r] = *(const float4*)(Wl + r * H_ + k);
                #pragma unroll
                for (int r = 0; r < 12; ++r) {
                    #pragma unroll
                    for (int bb = 0; bb < 8; ++bb) {
                        acc[r][bb] += w4[r].x * h4[bb].x;
                        acc[r][bb] += w4[r].y * h4[bb].y;
                        acc[r][bb] += w4[r].z * h4[bb].z;
                        acc[r][bb] += w4[r].w * h4[bb].w;
                    }
                }
            }
        }

        // ---- spill partials: red[tid][(r*2+bh)*4 + e] ----
        #pragma unroll
        for (int r = 0; r < 12; ++r) {
            #pragma unroll
            for (int bh = 0; bh < 2; ++bh) {
                const float4 v = make_float4(acc[r][bh*4+0], acc[r][bh*4+1],
                                             acc[r][bh*4+2], acc[r][bh*4+3]);
                *(float4*)(red + (size_t)tid * 100 + (r*2 + bh) * 4) = v;
            }
        }
        __syncthreads();

        // ---- reduce across 64 k-slices ----
        if (tid < 96) {
            const int r   = tid >> 3;
            const int bq2 = (tid >> 1) & 3;
            const int bh  = tid & 1;
            const int a4  = r*2 + bh;
            float4 s = make_float4(0.f, 0.f, 0.f, 0.f);
            #pragma unroll 8
            for (int q = 0; q < 64; ++q) {
                const float4 v = *(const float4*)(red + (size_t)(bq2*64 + q) * 100 + a4 * 4);
                s.x += v.x; s.y += v.y; s.z += v.z; s.w += v.w;
            }
            s.x += rbias; s.y += rbias; s.z += rbias; s.w += rbias;
            *(float4*)(ghl + r * 32 + bq2*8 + bh*4) = s;
        }
        __syncthreads();

        // ---- gate math + writes (threads 0..127) ----
        if (tid < 128) {
            const float hr = ghl[(0*4 + gjj) * 32 + gb];
            const float hz = ghl[(1*4 + gjj) * 32 + gb];
            const float hn = ghl[(2*4 + gjj) * 32 + gb];
            const float rg = 1.f / (1.f + __expf(-(xg0 + hr)));
            const float zg = 1.f / (1.f + __expf(-(xg1 + hz)));
            const float tn = xg2 + rg * hn;
            const float e  = __expf(-2.f * fabsf(tn));
            const float m  = (1.f - e) / (1.f + e);
            const float ng = copysignf(m, tn);          // tanh, inf-safe
            const float hnew = (1.f - zg) * ng + zg * hold;

            hnxt[(size_t)gb * H_ + j0 + gjj] = hnew;
            outp[((size_t)gb * T_ + t) * H_ + j0 + gjj] = hnew;
            if (t == T_ - 1) hidout[(size_t)gb * H_ + j0 + gjj] = hnew;
        }

        // ---- hand-rolled grid barrier (flag per block, monotone values) ----
        __syncthreads();                    // drain all block stores (vmcnt(0))
        if (tid == 0) {
            __threadfence();                // agent fence: wb local XCD L2
            __hip_atomic_store(&flags[bid * 32], t + 1,
                               __ATOMIC_RELEASE, __HIP_MEMORY_SCOPE_AGENT);
        }
        {   // each thread polls one block's flag (NTHR == NBLK)
            int v;
            do {
                v = __hip_atomic_load(&flags[tid * 32], __ATOMIC_RELAXED,
                                      __HIP_MEMORY_SCOPE_AGENT);
                if (v <= t) __builtin_amdgcn_s_sleep(1);
            } while (v <= t);
        }
        __threadfence();                    // acquire side: inv stale L2 lines
        __syncthreads();
    }
}

extern "C" void kernel_launch(void* const* d_in, const int* in_sizes, int n_in,
                              void* d_out, int out_size, void* d_ws, size_t ws_size,
                              hipStream_t stream) {
    const int*   xs  = (const int*)  d_in[0];
    const float* Wih = (const float*)d_in[1];
    const float* Whh = (const float*)d_in[2];
    const float* bih = (const float*)d_in[3];
    const float* bhh = (const float*)d_in[4];

    float* outp = (float*)d_out;
    float* hid  = outp + (size_t)B_ * T_ * H_;

    float* hA    = (float*)d_ws;
    float* hB    = hA + (size_t)B_ * H_;
    int*   flags = (int*)(hB + (size_t)B_ * H_);

    // zero the barrier flags every launch (graph-replay deterministic)
    (void)hipMemsetAsync(flags, 0, (size_t)NBLK * 32 * sizeof(int), stream);

    const size_t LDSB = (size_t)LDS_FLOATS * sizeof(float);   // 153088 B
    (void)hipFuncSetAttribute((const void*)gru_persist,
                              hipFuncAttributeMaxDynamicSharedMemorySize,
                              (int)LDSB);

    gru_persist<<<NBLK, NTHR, LDSB, stream>>>(
        Whh, bhh, Wih, bih, xs, hA, hB, flags, outp, hid);

    (void)in_sizes; (void)n_in; (void)out_size; (void)ws_size;
}

// Round 4
// 1180.254 us; speedup vs baseline: 3.6606x; 3.6606x over previous
//
#include <hip/hip_runtime.h>
#include <cstdint>
#include <cstddef>

#define B_   32
#define T_   128
#define H_   1024
#define V_   32000
#define NBLK 256
#define NTHR 256
#define JB   4        // hidden columns per block -> 12 W_hh rows
#define BH_  (B_*H_)  // 32768 floats per h buffer

// LDS layout (floats):
//   Wl  [12][1024]  12288   (W_hh tile, resident across all 128 steps)
//   red [256][100]  25600   (k-split partial spill; 400B row stride -> bank walk)
//   ghl [12][32]      384   (reduced gh tile)
#define LDS_WL_OFF   0
#define LDS_RED_OFF  (12*1024)
#define LDS_GHL_OFF  (12*1024 + 256*100)
#define LDS_FLOATS   (12*1024 + 256*100 + 12*32)

__global__ __launch_bounds__(NTHR) void gru_persist(
    const float* __restrict__ Whh,   // (3072,1024)
    const float* __restrict__ bhh,   // (3072)
    const float* __restrict__ Wih,   // (3072,32000)
    const float* __restrict__ bih,   // (3072)
    const int*   __restrict__ xs,    // (B,T)
    float*       __restrict__ hbase, // T_ x (B,H) step buffers (address-rotated)
    int*         __restrict__ flags, // (NBLK*32) zeroed before launch
    float*       __restrict__ outp,  // (B,T,H)
    float*       __restrict__ hidout)// (B,H)
{
    extern __shared__ float lds[];
    float* Wl  = lds + LDS_WL_OFF;
    float* red = lds + LDS_RED_OFF;
    float* ghl = lds + LDS_GHL_OFF;

    const int tid = threadIdx.x;
    const int bid = (int)blockIdx.x;
    const int j0  = bid * JB;

    // ---- stage W_hh tile into LDS ONCE (12 rows x 1024, float4 coalesced) ----
    #pragma unroll
    for (int i = 0; i < 12; ++i) {
        const int idx = i * NTHR + tid;   // float4 index 0..3071
        const int r   = idx >> 8;         // row 0..11
        const int kv  = idx & 255;
        const int g   = r >> 2, jj = r & 3;
        ((float4*)(Wl + r * H_))[kv] =
            ((const float4*)(Whh + (size_t)(g*H_ + j0 + jj) * H_))[kv];
    }

    const int gjj = tid & 3;   // gate-phase column-within-block
    const int gb  = tid >> 2;  // gate-phase batch
    const int kq  = tid & 63;  // GEMM k-slice lane
    const int bq  = tid >> 6;  // GEMM batch quad (wave id)

    // reduce-thread constants
    float rbias = 0.f;
    if (tid < 96) {
        const int r = tid >> 3;
        rbias = bhh[(r >> 2) * H_ + j0 + (r & 3)];
    }

    // gate-phase constants + gather prefetch for t=0
    const size_t gr0 = (size_t)(0*H_ + j0 + gjj) * V_;
    const size_t gr1 = (size_t)(1*H_ + j0 + gjj) * V_;
    const size_t gr2 = (size_t)(2*H_ + j0 + gjj) * V_;
    float bih0 = 0.f, bih1 = 0.f, bih2 = 0.f;
    float nxg0 = 0.f, nxg1 = 0.f, nxg2 = 0.f;
    if (tid < 128) {
        bih0 = bih[0*H_ + j0 + gjj];
        bih1 = bih[1*H_ + j0 + gjj];
        bih2 = bih[2*H_ + j0 + gjj];
        const int tok = xs[gb * T_];
        nxg0 = Wih[gr0 + tok];
        nxg1 = Wih[gr1 + tok];
        nxg2 = Wih[gr2 + tok];
    }

    __syncthreads();   // W tile ready

    for (int t = 0; t < T_; ++t) {
        // address-rotated h buffers: read hstep[t-1], write hstep[t].
        // Fresh read addresses every step -> consumer L2 can never hold a
        // stale copy -> plain (vectorized) loads are coherence-safe.
        const float* __restrict__ hcur = hbase + (size_t)(t > 0 ? t - 1 : 0) * BH_;
        float*       __restrict__ hnxt = hbase + (size_t)t * BH_;

        // consume prefetched gather; issue h_old load early
        const float xg0 = nxg0 + bih0;
        const float xg1 = nxg1 + bih1;
        const float xg2 = nxg2 + bih2;
        float hold = 0.f;
        if (tid < 128 && t > 0) hold = hcur[(size_t)gb * H_ + j0 + gjj];

        // issue NEXT step's scattered W_ih gather; latency hides under GEMM
        if (tid < 128 && t + 1 < T_) {
            const int tok = xs[gb * T_ + t + 1];
            nxg0 = Wih[gr0 + tok];
            nxg1 = Wih[gr1 + tok];
            nxg2 = Wih[gr2 + tok];
        }

        // ---- GEMM: gh(12 x 32) = W(12x1024) . h(32x1024)^T, 64-way k-split ----
        float acc[12][8];
        #pragma unroll
        for (int r = 0; r < 12; ++r)
            #pragma unroll
            for (int bb = 0; bb < 8; ++bb) acc[r][bb] = 0.f;

        if (t > 0) {
            #pragma unroll
            for (int c = 0; c < 4; ++c) {
                const int k = kq * 4 + c * 256;
                float4 h4[8];
                #pragma unroll
                for (int bb = 0; bb < 8; ++bb)
                    h4[bb] = *(const float4*)(hcur + (size_t)(bq*8 + bb) * H_ + k);
                float4 w4[12];
                #pragma unroll
                for (int r = 0; r < 12; ++r)
                    w4[r] = *(const float4*)(Wl + r * H_ + k);
                #pragma unroll
                for (int r = 0; r < 12; ++r) {
                    #pragma unroll
                    for (int bb = 0; bb < 8; ++bb) {
                        acc[r][bb] += w4[r].x * h4[bb].x;
                        acc[r][bb] += w4[r].y * h4[bb].y;
                        acc[r][bb] += w4[r].z * h4[bb].z;
                        acc[r][bb] += w4[r].w * h4[bb].w;
                    }
                }
            }
        }

        // ---- spill partials: red[tid][(r*2+bh)*4 + e] ----
        #pragma unroll
        for (int r = 0; r < 12; ++r) {
            #pragma unroll
            for (int bh = 0; bh < 2; ++bh) {
                const float4 v = make_float4(acc[r][bh*4+0], acc[r][bh*4+1],
                                             acc[r][bh*4+2], acc[r][bh*4+3]);
                *(float4*)(red + (size_t)tid * 100 + (r*2 + bh) * 4) = v;
            }
        }
        __syncthreads();

        // ---- reduce across 64 k-slices ----
        if (tid < 96) {
            const int r   = tid >> 3;
            const int bq2 = (tid >> 1) & 3;
            const int bh  = tid & 1;
            const int a4  = r*2 + bh;
            float4 s = make_float4(0.f, 0.f, 0.f, 0.f);
            #pragma unroll 8
            for (int q = 0; q < 64; ++q) {
                const float4 v = *(const float4*)(red + (size_t)(bq2*64 + q) * 100 + a4 * 4);
                s.x += v.x; s.y += v.y; s.z += v.z; s.w += v.w;
            }
            s.x += rbias; s.y += rbias; s.z += rbias; s.w += rbias;
            *(float4*)(ghl + r * 32 + bq2*8 + bh*4) = s;
        }
        __syncthreads();

        // ---- gate math + writes (threads 0..127) ----
        if (tid < 128) {
            const float hr = ghl[(0*4 + gjj) * 32 + gb];
            const float hz = ghl[(1*4 + gjj) * 32 + gb];
            const float hn = ghl[(2*4 + gjj) * 32 + gb];
            const float rg = 1.f / (1.f + __expf(-(xg0 + hr)));
            const float zg = 1.f / (1.f + __expf(-(xg1 + hz)));
            const float tn = xg2 + rg * hn;
            const float e  = __expf(-2.f * fabsf(tn));
            const float m  = (1.f - e) / (1.f + e);
            const float ng = copysignf(m, tn);          // tanh, inf-safe
            const float hnew = (1.f - zg) * ng + zg * hold;

            // device-coherent write-through (sc1) past the XCD-local L2;
            // relaxed -> NO buffer_wbl2 / buffer_inv is ever emitted.
            __hip_atomic_store(&hnxt[(size_t)gb * H_ + j0 + gjj], hnew,
                               __ATOMIC_RELAXED, __HIP_MEMORY_SCOPE_AGENT);
            outp[((size_t)gb * T_ + t) * H_ + j0 + gjj] = hnew;   // plain; kernel-end flush
            if (t == T_ - 1) hidout[(size_t)gb * H_ + j0 + gjj] = hnew;
        }

        // ---- fence-free grid barrier ----
        // __syncthreads emits s_waitcnt vmcnt(0) per wave -> every wave's sc1
        // h-stores have reached the coherence point before tid0 sets the flag.
        __syncthreads();
        if (tid == 0) {
            __hip_atomic_store(&flags[bid * 32], t + 1,
                               __ATOMIC_RELAXED, __HIP_MEMORY_SCOPE_AGENT);
        }
        {   // each thread polls one block's flag (NTHR == NBLK); sc1 loads
            // bypass stale L1/L2 by construction.
            int v;
            do {
                v = __hip_atomic_load(&flags[tid * 32], __ATOMIC_RELAXED,
                                      __HIP_MEMORY_SCOPE_AGENT);
                if (v <= t) __builtin_amdgcn_s_sleep(1);
            } while (v <= t);
        }
        asm volatile("" ::: "memory");  // keep next step's loads below the poll
        __syncthreads();
    }
}

extern "C" void kernel_launch(void* const* d_in, const int* in_sizes, int n_in,
                              void* d_out, int out_size, void* d_ws, size_t ws_size,
                              hipStream_t stream) {
    const int*   xs  = (const int*)  d_in[0];
    const float* Wih = (const float*)d_in[1];
    const float* Whh = (const float*)d_in[2];
    const float* bih = (const float*)d_in[3];
    const float* bhh = (const float*)d_in[4];

    float* outp = (float*)d_out;
    float* hid  = outp + (size_t)B_ * T_ * H_;

    float* hbase = (float*)d_ws;                       // T_ * 128KB = 16 MB
    int*   flags = (int*)(hbase + (size_t)T_ * BH_);

    // zero the barrier flags every launch (graph-replay deterministic)
    (void)hipMemsetAsync(flags, 0, (size_t)NBLK * 32 * sizeof(int), stream);

    const size_t LDSB = (size_t)LDS_FLOATS * sizeof(float);   // 153088 B
    (void)hipFuncSetAttribute((const void*)gru_persist,
                              hipFuncAttributeMaxDynamicSharedMemorySize,
                              (int)LDSB);

    gru_persist<<<NBLK, NTHR, LDSB, stream>>>(
        Whh, bhh, Wih, bih, xs, hbase, flags, outp, hid);

    (void)in_sizes; (void)n_in; (void)out_size; (void)ws_size;
}

// Round 5
// 992.638 us; speedup vs baseline: 4.3525x; 1.1890x over previous
//
#include <hip/hip_runtime.h>
#include <cstdint>
#include <cstddef>

#define B_   32
#define T_   128
#define H_   1024
#define V_   32000
#define NBLK 256
#define NTHR 512
#define JB   4        // hidden columns per block -> 12 W_hh rows
#define BH_  (B_*H_)  // 32768 floats per h buffer
#define RST  52       // red row stride in floats (52%32=20 -> uniform bank walk)

// LDS layout (floats):
//   Wl  [12][1024]   12288  (W_hh tile, resident across all 128 steps)
//   red [512][52]    26624  (k-split partial spill)
//   ghl [12][32]       384  (reduced gh tile)
#define LDS_WL_OFF   0
#define LDS_RED_OFF  (12*1024)
#define LDS_GHL_OFF  (12*1024 + 512*RST)
#define LDS_FLOATS   (12*1024 + 512*RST + 12*32)

__global__ __launch_bounds__(NTHR) void gru_persist(
    const float* __restrict__ Whh,   // (3072,1024)
    const float* __restrict__ bhh,   // (3072)
    const float* __restrict__ Wih,   // (3072,32000)
    const float* __restrict__ bih,   // (3072)
    const int*   __restrict__ xs,    // (B,T)
    float*       __restrict__ hbase, // T_ x (B,H) step buffers (address-rotated)
    int*         __restrict__ flags, // (NBLK*32) zeroed before launch
    float*       __restrict__ outp,  // (B,T,H)
    float*       __restrict__ hidout)// (B,H)
{
    extern __shared__ float lds[];
    float* Wl  = lds + LDS_WL_OFF;
    float* red = lds + LDS_RED_OFF;
    float* ghl = lds + LDS_GHL_OFF;

    const int tid = threadIdx.x;
    const int bid = (int)blockIdx.x;
    const int j0  = bid * JB;

    // ---- stage W_hh tile into LDS ONCE (12 rows x 1024, float4 coalesced) ----
    #pragma unroll
    for (int i = 0; i < 6; ++i) {
        const int idx = i * NTHR + tid;   // float4 index 0..3071
        const int r   = idx >> 8;         // row 0..11
        const int kv  = idx & 255;
        const int g   = r >> 2, jj = r & 3;
        ((float4*)(Wl + r * H_))[kv] =
            ((const float4*)(Whh + (size_t)(g*H_ + j0 + jj) * H_))[kv];
    }

    const int gjj = tid & 3;          // gate-phase column-within-block
    const int gb  = tid >> 2;         // gate-phase batch
    const int kq  = tid & 63;         // GEMM k-slice lane
    const int bq4 = (tid >> 6) & 3;   // GEMM batch quad-of-4
    const int h16 = tid >> 8;         // GEMM batch half (0/1)
    const int b0  = h16 * 16 + bq4 * 4;  // first of this thread's 4 batches

    // reduce-thread constants
    float rbias = 0.f;
    if (tid < 96) {
        const int r = tid >> 3;
        rbias = bhh[(r >> 2) * H_ + j0 + (r & 3)];
    }

    // gate-phase constants + gather prefetch for t=0
    const size_t gr0 = (size_t)(0*H_ + j0 + gjj) * V_;
    const size_t gr1 = (size_t)(1*H_ + j0 + gjj) * V_;
    const size_t gr2 = (size_t)(2*H_ + j0 + gjj) * V_;
    float bih0 = 0.f, bih1 = 0.f, bih2 = 0.f;
    float nxg0 = 0.f, nxg1 = 0.f, nxg2 = 0.f;
    if (tid < 128) {
        bih0 = bih[0*H_ + j0 + gjj];
        bih1 = bih[1*H_ + j0 + gjj];
        bih2 = bih[2*H_ + j0 + gjj];
        const int tok = xs[gb * T_];
        nxg0 = Wih[gr0 + tok];
        nxg1 = Wih[gr1 + tok];
        nxg2 = Wih[gr2 + tok];
    }

    __syncthreads();   // W tile ready

    for (int t = 0; t < T_; ++t) {
        // address-rotated h buffers: read hstep[t-1], write hstep[t].
        // Fresh read addresses each step -> no stale L2 copies -> plain loads ok.
        const float* __restrict__ hcur = hbase + (size_t)(t > 0 ? t - 1 : 0) * BH_;
        float*       __restrict__ hnxt = hbase + (size_t)t * BH_;

        const float xg0 = nxg0 + bih0;
        const float xg1 = nxg1 + bih1;
        const float xg2 = nxg2 + bih2;
        float hold = 0.f;
        if (tid < 128 && t > 0) hold = hcur[(size_t)gb * H_ + j0 + gjj];

        // issue NEXT step's scattered W_ih gather; latency hides under GEMM
        if (tid < 128 && t + 1 < T_) {
            const int tok = xs[gb * T_ + t + 1];
            nxg0 = Wih[gr0 + tok];
            nxg1 = Wih[gr1 + tok];
            nxg2 = Wih[gr2 + tok];
        }

        // ---- GEMM: gh(12 x 32) = W(12x1024) . h(32x1024)^T ----
        // thread: 12 rows x 4 batches (b0..b0+3), k = kq*4 + c*256
        float acc[12][4];
        #pragma unroll
        for (int r = 0; r < 12; ++r)
            #pragma unroll
            for (int bb = 0; bb < 4; ++bb) acc[r][bb] = 0.f;

        if (t > 0) {
            #pragma unroll
            for (int c = 0; c < 4; ++c) {
                const int k = kq * 4 + c * 256;
                float4 h4[4];
                #pragma unroll
                for (int bb = 0; bb < 4; ++bb)
                    h4[bb] = *(const float4*)(hcur + (size_t)(b0 + bb) * H_ + k);
                float4 w4[12];
                #pragma unroll
                for (int r = 0; r < 12; ++r)
                    w4[r] = *(const float4*)(Wl + r * H_ + k);
                #pragma unroll
                for (int r = 0; r < 12; ++r) {
                    #pragma unroll
                    for (int bb = 0; bb < 4; ++bb) {
                        acc[r][bb] += w4[r].x * h4[bb].x;
                        acc[r][bb] += w4[r].y * h4[bb].y;
                        acc[r][bb] += w4[r].z * h4[bb].z;
                        acc[r][bb] += w4[r].w * h4[bb].w;
                    }
                }
            }
        }

        // ---- spill partials: red[tid][r*4 .. +4] ----
        #pragma unroll
        for (int r = 0; r < 12; ++r) {
            const float4 v = make_float4(acc[r][0], acc[r][1], acc[r][2], acc[r][3]);
            *(float4*)(red + (size_t)tid * RST + r * 4) = v;
        }
        __syncthreads();

        // ---- reduce across 64 k-slices (96 threads; q-phase vs bank alias) ----
        if (tid < 96) {
            const int r    = tid >> 3;      // 0..11
            const int bg   = tid & 7;       // batch-group of 4 (batches bg*4..+3)
            const int base = (bg >> 2) * 256 + (bg & 3) * 64;  // partial row base
            float4 s = make_float4(0.f, 0.f, 0.f, 0.f);
            #pragma unroll 8
            for (int qq = 0; qq < 64; ++qq) {
                const int q = (qq + bg * 9) & 63;
                const float4 v = *(const float4*)(red + (size_t)(base + q) * RST + r * 4);
                s.x += v.x; s.y += v.y; s.z += v.z; s.w += v.w;
            }
            s.x += rbias; s.y += rbias; s.z += rbias; s.w += rbias;
            *(float4*)(ghl + r * 32 + bg * 4) = s;   // ghl[r][b]
        }
        __syncthreads();

        // ---- gate math + writes (threads 0..127) ----
        if (tid < 128) {
            const float hr = ghl[(0*4 + gjj) * 32 + gb];
            const float hz = ghl[(1*4 + gjj) * 32 + gb];
            const float hn = ghl[(2*4 + gjj) * 32 + gb];
            const float rg = 1.f / (1.f + __expf(-(xg0 + hr)));
            const float zg = 1.f / (1.f + __expf(-(xg1 + hz)));
            const float tn = xg2 + rg * hn;
            const float e  = __expf(-2.f * fabsf(tn));
            const float m  = (1.f - e) / (1.f + e);
            const float ng = copysignf(m, tn);          // tanh, inf-safe
            const float hnew = (1.f - zg) * ng + zg * hold;

            // device-coherent write-through (sc1); relaxed -> no wbl2/inv emitted
            __hip_atomic_store(&hnxt[(size_t)gb * H_ + j0 + gjj], hnew,
                               __ATOMIC_RELAXED, __HIP_MEMORY_SCOPE_AGENT);
            outp[((size_t)gb * T_ + t) * H_ + j0 + gjj] = hnew;
            if (t == T_ - 1) hidout[(size_t)gb * H_ + j0 + gjj] = hnew;
        }

        // ---- fence-free grid barrier (monotone per-block flags) ----
        // __syncthreads drains each wave's sc1 stores (vmcnt(0)) before tid0
        // publishes; consumer sc1 polls bypass stale caches by construction.
        __syncthreads();
        if (tid == 0) {
            __hip_atomic_store(&flags[bid * 32], t + 1,
                               __ATOMIC_RELAXED, __HIP_MEMORY_SCOPE_AGENT);
        }
        if (tid < NBLK) {   // tight spin, no sleep
            int v;
            do {
                v = __hip_atomic_load(&flags[tid * 32], __ATOMIC_RELAXED,
                                      __HIP_MEMORY_SCOPE_AGENT);
            } while (v <= t);
        }
        asm volatile("" ::: "memory");  // keep next step's loads below the poll
        __syncthreads();
    }
}

extern "C" void kernel_launch(void* const* d_in, const int* in_sizes, int n_in,
                              void* d_out, int out_size, void* d_ws, size_t ws_size,
                              hipStream_t stream) {
    const int*   xs  = (const int*)  d_in[0];
    const float* Wih = (const float*)d_in[1];
    const float* Whh = (const float*)d_in[2];
    const float* bih = (const float*)d_in[3];
    const float* bhh = (const float*)d_in[4];

    float* outp = (float*)d_out;
    float* hid  = outp + (size_t)B_ * T_ * H_;

    float* hbase = (float*)d_ws;                       // T_ * 128KB = 16 MB
    int*   flags = (int*)(hbase + (size_t)T_ * BH_);

    // zero the barrier flags every launch (graph-replay deterministic)
    (void)hipMemsetAsync(flags, 0, (size_t)NBLK * 32 * sizeof(int), stream);

    const size_t LDSB = (size_t)LDS_FLOATS * sizeof(float);   // 157184 B
    (void)hipFuncSetAttribute((const void*)gru_persist,
                              hipFuncAttributeMaxDynamicSharedMemorySize,
                              (int)LDSB);

    gru_persist<<<NBLK, NTHR, LDSB, stream>>>(
        Whh, bhh, Wih, bih, xs, hbase, flags, outp, hid);

    (void)in_sizes; (void)n_in; (void)out_size; (void)ws_size;
}